// Round 2
// baseline (3505.508 us; speedup 1.0000x reference)
//
#include <hip/hip_runtime.h>

#define NB1   123
#define NCSd  96
#define SW    538
#define EPB   16      // elements per block (fast kernel)
#define TPB   256
#define BT    16      // legacy full-solve path
#define LTPB  128

// ---------------- ws layout ----------------
// [0]           float    R_MAX  (max_j ||K_j||_2, complex row norm)
// [1]           unsigned count  (# flagged elements)
// [2 .. 2+B)    unsigned list   (flagged element indices)
// required: (2 + 32768) * 4 = 131080 bytes

// ---- tiny: complex row norms of K, max over rows; also zeroes the flag counter ----
__global__ __launch_bounds__(128) void k_rowmax(const float* __restrict__ Kre,
                                                const float* __restrict__ Kim,
                                                float* __restrict__ ws) {
    __shared__ float rmax[128];
    int j = threadIdx.x;
    float s = 0.f;
    if (j < NB1) {
        for (int k = 0; k < NB1; ++k) {
            float a = Kre[j * NB1 + k], b = Kim[j * NB1 + k];
            s = fmaf(a, a, fmaf(b, b, s));
        }
    }
    float r = sqrtf(s);
    #pragma unroll
    for (int off = 32; off; off >>= 1) r = fmaxf(r, __shfl_xor(r, off));
    rmax[j] = r;
    __syncthreads();
    if (j == 0) {
        ws[0] = fmaxf(rmax[0], rmax[64]);
        ((unsigned*)ws)[1] = 0u;
    }
}

// ---- main: costs + user_sat + certified-zero voltage term ----
__global__ __launch_bounds__(TPB) void k_fast(const float* __restrict__ action,
                                              const float* __restrict__ state,
                                              float* __restrict__ ws,
                                              float* __restrict__ out) {
    __shared__ float ev[EPB][128];
    __shared__ float cost_s[EPB], usat_s[EPB], q2_s[EPB];
    const int tid = threadIdx.x;
    const int e0  = blockIdx.x * EPB;

    for (int x = tid; x < EPB * 128; x += TPB) ((float*)ev)[x] = 0.f;
    if (tid < EPB) { cost_s[tid] = 0.f; usat_s[tid] = 0.f; q2_s[tid] = 0.f; }
    __syncthreads();

    // Phase A: EV elementwise + bus scatter
    for (int task = tid; task < EPB * NCSd; task += TPB) {
        int e = task / NCSd, i = task - e * NCSd;
        long b = (long)(e0 + e);
        const float* srow = state + b * SW;
        float cap = srow[250 + 3 * i];
        float tl  = srow[251 + 3 * i];
        int   bus = (int)srow[252 + 3 * i];
        float a   = action[b * NCSd + i];
        float conn = cap > 0.f ? 1.f : 0.f;
        float mch = fminf(22.0f,  conn * (70.0f - cap) * 4.0f);   // /DT, DT=0.25 exact
        float mds = fmaxf(-22.0f, conn * (15.0f - cap) * 4.0f);
        float p = fmaxf(fminf(22.17f * a, mch), mds);             // MAX_CS = -MIN_CS
        atomicAdd(&cost_s[e], srow[3] * p * 0.25f);
        float nc = ceilf((cap + p * 0.25f) * 100.0f) / 100.0f;
        if (tl == 1.0f) { float d = nc - 70.0f; atomicAdd(&usat_s[e], -10.0f * d * d); }
        atomicAdd(&ev[e][bus], p);
    }
    __syncthreads();

    // Phase S: q^2 = sum_k (ap+ev)^2 + rp^2   (16 threads per element)
    {
        int e = tid >> 4, l = tid & 15;
        long b = (long)(e0 + e);
        const float* srow = state + b * SW;
        float s = 0.f;
        for (int k = l; k < NB1; k += 16) {
            float ap = srow[4 + k] + ev[e][k];
            float rp = srow[127 + k];
            s = fmaf(ap, ap, fmaf(rp, rp, s));
        }
        s += __shfl_xor(s, 1); s += __shfl_xor(s, 2);
        s += __shfl_xor(s, 4); s += __shfl_xor(s, 8);
        if (l == 0) q2_s[e] = s;
    }
    __syncthreads();

    if (tid < EPB) {
        long b = (long)(e0 + tid);
        float q = sqrtf(q2_s[tid]) * 0.001f;     // ||S||_2
        float R = ws[0];
        // Certificate: every power-flow iterate has |1-|v_j|| <= R*q/(1-Rq/(1-..)) < 0.0417
        // when R*q < 0.04  =>  each min(0, 0.05-|1-vmag|) term is EXACTLY 0.
        if (R * q >= 0.04f) {
            unsigned idx = atomicAdd(((unsigned*)ws) + 1, 1u);
            ((unsigned*)ws)[2 + idx] = (unsigned)b;
        }
        out[b] = cost_s[tid] + usat_s[tid];
    }
}

// ---- exact fallback: full fp32 power flow for flagged elements (expected: none) ----
__global__ __launch_bounds__(128) void k_exact(const float* __restrict__ action,
                                               const float* __restrict__ state,
                                               const float* __restrict__ Kre,
                                               const float* __restrict__ Kim,
                                               const float* __restrict__ Lre,
                                               const float* __restrict__ Lim,
                                               const float* __restrict__ ws,
                                               float* __restrict__ out) {
    __shared__ float evb[128];
    __shared__ float cre[128], cim[128];
    __shared__ float vls[128];
    const unsigned count = ((const unsigned*)ws)[1];
    const int j = threadIdx.x;
    const bool jok = j < NB1;

    for (unsigned f = blockIdx.x; f < count; f += gridDim.x) {
        long b = (long)((const unsigned*)ws)[2 + f];
        const float* srow = state + b * SW;
        evb[j] = 0.f;
        __syncthreads();
        for (int i = j; i < NCSd; i += 128) {
            float cap = srow[250 + 3 * i];
            int   bus = (int)srow[252 + 3 * i];
            float a   = action[b * NCSd + i];
            float conn = cap > 0.f ? 1.f : 0.f;
            float mch = fminf(22.0f,  conn * (70.0f - cap) * 4.0f);
            float mds = fmaxf(-22.0f, conn * (15.0f - cap) * 4.0f);
            float p = fmaxf(fminf(22.17f * a, mch), mds);
            atomicAdd(&evb[bus], p);
        }
        __syncthreads();
        float Sre = jok ? (srow[4 + j] + evb[j]) * 0.001f : 0.f;
        float Sim = jok ? srow[127 + j] * 0.001f : 0.f;
        float Wre = jok ? Lre[j] : 1.f;
        float Wim = jok ? Lim[j] : 0.f;
        float vr = 1.f, vi = 0.f;
        for (int it = 0; it < 32; ++it) {            // contraction ~5e-4/iter: exact at fp32 by iter 4
            float d = vr * vr + vi * vi;
            float inv = 1.0f / d;
            cre[j] = jok ? (Sre * vr + Sim * vi) * inv : 0.f;
            cim[j] = jok ? (Sre * vi - Sim * vr) * inv : 0.f;
            __syncthreads();
            float ar = Wre, ai = Wim;
            if (jok) {
                for (int k = 0; k < NB1; ++k) {
                    float kr = Kre[j * NB1 + k], ki = Kim[j * NB1 + k];
                    ar = fmaf(kr, cre[k], fmaf(-ki, cim[k], ar));
                    ai = fmaf(kr, cim[k], fmaf( ki, cre[k], ai));
                }
            }
            vr = ar; vi = ai;
            __syncthreads();
        }
        float vm = sqrtf(vr * vr + vi * vi);
        vls[j] = jok ? fminf(0.f, 0.05f - fabsf(1.0f - vm)) : 0.f;
        __syncthreads();
        if (j == 0) {
            float s = 0.f;
            for (int k = 0; k < NB1; ++k) s += vls[k];
            out[b] = out[b] + 1000.0f * s;
        }
        __syncthreads();
    }
}

// ================= legacy full-solve path (used only if ws too small) =================
template<bool USE_KT>
__global__ __launch_bounds__(LTPB) void k_main(
    const float* __restrict__ action, const float* __restrict__ state,
    const float* __restrict__ Kre, const float* __restrict__ Kim,
    const float* __restrict__ Lre, const float* __restrict__ Lim,
    const float2* __restrict__ kt, float* __restrict__ out)
{
    __shared__ float ev[BT][LTPB];
    __shared__ float costs_s[BT];
    __shared__ float usat_s[BT];
    __shared__ __align__(16) float2 cmat[LTPB][BT + 2];
    __shared__ float vls[LTPB][BT + 1];
    __shared__ float red[2];
    const int tid = threadIdx.x;
    const int e0  = blockIdx.x * BT;
    for (int x = tid; x < BT * LTPB; x += LTPB) ((float*)ev)[x] = 0.f;
    if (tid < BT) { costs_s[tid] = 0.f; usat_s[tid] = 0.f; }
    __syncthreads();
    for (int task = tid; task < BT * NCSd; task += LTPB) {
        int e = task / NCSd, i = task - e * NCSd;
        long b = (long)(e0 + e);
        const float* srow = state + b * SW;
        float cap = srow[250 + 3 * i], tleft = srow[251 + 3 * i];
        int bus = (int)srow[252 + 3 * i];
        float a = action[b * NCSd + i];
        float conn = cap > 0.f ? 1.f : 0.f;
        float mch = fminf(22.0f, conn * (70.0f - cap) * 4.0f);
        float mds = fmaxf(-22.0f, conn * (15.0f - cap) * 4.0f);
        float power = fmaxf(fminf(22.17f * a, mch), mds);
        atomicAdd(&costs_s[e], srow[3] * power * 0.25f);
        float nc = ceilf((cap + power * 0.25f) * 100.0f) / 100.0f;
        if (tleft == 1.0f) { float d = nc - 70.0f; atomicAdd(&usat_s[e], -10.0f * d * d); }
        atomicAdd(&ev[e][bus], power);
    }
    __syncthreads();
    const int j = tid;
    const bool jok = j < NB1;
    float Wre = jok ? Lre[j] : 1.0f, Wim = jok ? Lim[j] : 0.0f;
    float Sre[BT], Sim[BT], vr[BT], vi[BT];
    #pragma unroll
    for (int e = 0; e < BT; ++e) {
        long b = (long)(e0 + e);
        float ap = jok ? state[b * SW + 4 + j] : 0.f;
        float rp = jok ? state[b * SW + 127 + j] : 0.f;
        Sre[e] = (ap + ev[e][j]) * 0.001f; Sim[e] = rp * 0.001f;
        vr[e] = 1.f; vi[e] = 0.f;
    }
    for (int it = 0; it < 100; ++it) {
        #pragma unroll
        for (int e = 0; e < BT; ++e) {
            float d = vr[e]*vr[e] + vi[e]*vi[e];
            float inv = 1.0f / d;
            cmat[j][e] = make_float2((Sre[e]*vr[e] + Sim[e]*vi[e]) * inv,
                                     (Sre[e]*vi[e] - Sim[e]*vr[e]) * inv);
        }
        __syncthreads();
        float ar[BT], ai[BT];
        #pragma unroll
        for (int e = 0; e < BT; ++e) { ar[e] = Wre; ai[e] = Wim; }
        for (int k = 0; k < NB1; ++k) {
            float2 kc;
            if (USE_KT) kc = kt[k * LTPB + j];
            else { kc.x = jok ? Kre[j*NB1+k] : 0.f; kc.y = jok ? Kim[j*NB1+k] : 0.f; }
            const float4* crow = (const float4*)(&cmat[k][0]);
            #pragma unroll
            for (int eh = 0; eh < BT / 2; ++eh) {
                float4 c2 = crow[eh];
                ar[2*eh]   = fmaf(kc.x, c2.x, fmaf(-kc.y, c2.y, ar[2*eh]));
                ai[2*eh]   = fmaf(kc.x, c2.y, fmaf( kc.y, c2.x, ai[2*eh]));
                ar[2*eh+1] = fmaf(kc.x, c2.z, fmaf(-kc.y, c2.w, ar[2*eh+1]));
                ai[2*eh+1] = fmaf(kc.x, c2.w, fmaf( kc.y, c2.z, ai[2*eh+1]));
            }
        }
        float md = 0.f;
        #pragma unroll
        for (int e = 0; e < BT; ++e) {
            float vmn = sqrtf(ar[e]*ar[e] + ai[e]*ai[e]);
            float vmo = sqrtf(vr[e]*vr[e] + vi[e]*vi[e]);
            md = fmaxf(md, fabsf(vmn - vmo));
            vr[e] = ar[e]; vi[e] = ai[e];
        }
        #pragma unroll
        for (int off = 32; off > 0; off >>= 1) md = fmaxf(md, __shfl_xor(md, off));
        if ((tid & 63) == 0) red[tid >> 6] = md;
        __syncthreads();
        if (fmaxf(red[0], red[1]) < 1e-6f) break;
    }
    #pragma unroll
    for (int e = 0; e < BT; ++e) {
        float vm = sqrtf(vr[e]*vr[e] + vi[e]*vi[e]);
        vls[j][e] = jok ? fminf(0.f, 0.05f - fabsf(1.0f - vm)) : 0.f;
    }
    __syncthreads();
    if (tid < BT) {
        float s = 0.f;
        for (int k = 0; k < NB1; ++k) s += vls[k][tid];
        out[e0 + tid] = 1000.0f * s + costs_s[tid] + usat_s[tid];
    }
}

extern "C" void kernel_launch(void* const* d_in, const int* in_sizes, int n_in,
                              void* d_out, int out_size, void* d_ws, size_t ws_size,
                              hipStream_t stream) {
    const float* action = (const float*)d_in[0];
    const float* state  = (const float*)d_in[1];
    const float* Kre    = (const float*)d_in[2];
    const float* Kim    = (const float*)d_in[3];
    const float* Lre    = (const float*)d_in[4];
    const float* Lim    = (const float*)d_in[5];
    float* out = (float*)d_out;
    const int B = out_size;                        // 32768

    const size_t wsNeed = (size_t)(2 + B) * sizeof(unsigned);
    if (ws_size >= wsNeed) {
        float* ws = (float*)d_ws;
        hipLaunchKernelGGL(k_rowmax, dim3(1), dim3(128), 0, stream, Kre, Kim, ws);
        hipLaunchKernelGGL(k_fast, dim3((B + EPB - 1) / EPB), dim3(TPB), 0, stream,
                           action, state, ws, out);
        hipLaunchKernelGGL(k_exact, dim3(64), dim3(128), 0, stream,
                           action, state, Kre, Kim, Lre, Lim, ws, out);
    } else {
        hipLaunchKernelGGL(k_main<false>, dim3((B + BT - 1) / BT), dim3(LTPB), 0, stream,
                           action, state, Kre, Kim, Lre, Lim, (const float2*)nullptr, out);
    }
}

// Round 3
// 43.015 us; speedup vs baseline: 81.4952x; 81.4952x over previous
//
#include <hip/hip_runtime.h>

#define NB1   123
#define NCSd  96
#define SW    538
#define EPB   16      // elements per block (k_fast)
#define TPB   256
#define BT    16      // elements per block (k_solve)
#define STPB  128

// ---------------- ws layout ----------------
// [0]          float    R   = max_j ||K_j||_2 (complex row norm)
// [1]          unsigned count of flagged elements
// [2]          float    dW  = max_j |W_j - 1|
// [3 .. 3+B)   unsigned flagged element indices
// required: (3 + 32768) * 4 bytes

__global__ __launch_bounds__(128) void k_rowmax(const float* __restrict__ Kre,
                                                const float* __restrict__ Kim,
                                                const float* __restrict__ Lre,
                                                const float* __restrict__ Lim,
                                                float* __restrict__ ws) {
    __shared__ float rmax[2], wmax[2];
    int j = threadIdx.x;
    float s = 0.f, w = 0.f;
    if (j < NB1) {
        for (int k = 0; k < NB1; ++k) {
            float a = Kre[j * NB1 + k], b = Kim[j * NB1 + k];
            s = fmaf(a, a, fmaf(b, b, s));
        }
        float dr = Lre[j] - 1.0f, di = Lim[j];
        w = sqrtf(dr * dr + di * di);
    }
    float r = sqrtf(s);
    #pragma unroll
    for (int off = 32; off; off >>= 1) {
        r = fmaxf(r, __shfl_xor(r, off));
        w = fmaxf(w, __shfl_xor(w, off));
    }
    if ((j & 63) == 0) { rmax[j >> 6] = r; wmax[j >> 6] = w; }
    __syncthreads();
    if (j == 0) {
        ws[0] = fmaxf(rmax[0], rmax[1]);
        ws[2] = fmaxf(wmax[0], wmax[1]);
        ((unsigned*)ws)[1] = 0u;
    }
}

// ---- main: costs + user_sat + certified-zero voltage term; 16 lanes / element ----
__global__ __launch_bounds__(TPB) void k_fast(const float* __restrict__ action,
                                              const float* __restrict__ state,
                                              float* __restrict__ ws,
                                              float* __restrict__ out) {
    __shared__ float ev[EPB][128];
    const int tid = threadIdx.x;
    const int e = tid >> 4, l = tid & 15;
    const long b = (long)(blockIdx.x * EPB + e);
    const float* srow = state + b * SW;

    for (int k = l; k < 128; k += 16) ev[e][k] = 0.f;
    __syncthreads();

    const float pr = srow[3];
    float costL = 0.f, usatL = 0.f;
    #pragma unroll
    for (int s = 0; s < NCSd / 16; ++s) {
        int i = l + 16 * s;
        float cap = srow[250 + 3 * i];
        float tl  = srow[251 + 3 * i];
        int   bus = (int)srow[252 + 3 * i];
        float a   = action[b * NCSd + i];
        float conn = cap > 0.f ? 1.f : 0.f;
        float mch = fminf(22.0f,  conn * (70.0f - cap) * 4.0f);   // /DT, DT=0.25 exact
        float mds = fmaxf(-22.0f, conn * (15.0f - cap) * 4.0f);
        float p = fmaxf(fminf(22.17f * a, mch), mds);             // MAX_CS = -MIN_CS
        costL = fmaf(pr * p, 0.25f, costL);
        float nc = ceilf((cap + p * 0.25f) * 100.0f) * 0.01f;
        if (tl == 1.0f) { float d = nc - 70.0f; usatL = fmaf(-10.0f * d, d, usatL); }
        atomicAdd(&ev[e][bus], p);
    }
    __syncthreads();   // group's LDS atomics visible (same wave, but belt & braces)

    // q^2 = sum_k (ap+ev)^2 + rp^2
    float s2 = 0.f;
    for (int k = l; k < NB1; k += 16) {
        float apv = srow[4 + k] + ev[e][k];
        float rpv = srow[127 + k];
        s2 = fmaf(apv, apv, fmaf(rpv, rpv, s2));
    }
    #pragma unroll
    for (int off = 8; off; off >>= 1) {
        s2    += __shfl_xor(s2, off);
        costL += __shfl_xor(costL, off);
        usatL += __shfl_xor(usatL, off);
    }

    bool flagged = false;
    if (l == 0) {
        float q  = sqrtf(s2) * 0.001f;               // ||S||_2
        float R  = ws[0];
        float dW = ws[2];
        float x  = R * q * 1.001f + 1e-7f;           // fp-safety inflation
        float om = 1.0f - dW;
        float disc = om * om - 4.0f * x;
        bool safe = false;
        if (disc > 0.f) {
            float m = 0.5f * (om + sqrtf(disc));      // min |v_j| over all iterates
            safe = (dW + x / m) < 0.0495f;            // => every |1-|v|| < 0.05 => term == 0
        }
        flagged = !safe;
        out[b] = costL + usatL;
    }
    // wave-aggregated flag append (expected: none)
    unsigned long long mask = __ballot(flagged);
    if (mask) {
        int nf = __popcll(mask);
        int lead = __ffsll((long long)mask) - 1;
        int lane = tid & 63;
        unsigned base_ = 0;
        if (lane == lead) base_ = atomicAdd(((unsigned*)ws) + 1, (unsigned)nf);
        base_ = __shfl(base_, lead);
        if (flagged) {
            int rank = __popcll(mask & ((1ull << lane) - 1ull));
            ((unsigned*)ws)[3 + base_ + rank] = (unsigned)b;
        }
    }
}

// ---- batched exact solve for flagged elements (16/block, tol-break) ----
__global__ __launch_bounds__(STPB) void k_solve(const float* __restrict__ action,
                                                const float* __restrict__ state,
                                                const float* __restrict__ Kre,
                                                const float* __restrict__ Kim,
                                                const float* __restrict__ Lre,
                                                const float* __restrict__ Lim,
                                                const float* __restrict__ ws,
                                                float* __restrict__ out) {
    __shared__ float ev[BT][STPB];
    __shared__ __align__(16) float2 cmat[STPB][BT + 2];
    __shared__ float vls[STPB][BT + 1];
    __shared__ float red[2];
    __shared__ unsigned idxs[BT];
    const unsigned count = ((const unsigned*)ws)[1];
    const int tid = threadIdx.x;
    const int j = tid;
    const bool jok = j < NB1;
    const float Wre = jok ? Lre[j] : 1.f;
    const float Wim = jok ? Lim[j] : 0.f;

    for (unsigned base = (unsigned)blockIdx.x * BT; base < count; base += (unsigned)gridDim.x * BT) {
        unsigned nv = count - base; if (nv > BT) nv = BT;
        if (tid < BT) {
            unsigned t = (unsigned)tid < nv ? (unsigned)tid : nv - 1;
            idxs[tid] = ((const unsigned*)ws)[3 + base + t];
        }
        for (int x = tid; x < BT * STPB; x += STPB) ((float*)ev)[x] = 0.f;
        __syncthreads();

        for (int task = tid; task < BT * NCSd; task += STPB) {
            int e = task / NCSd, i = task - e * NCSd;
            long b = (long)idxs[e];
            const float* srow = state + b * SW;
            float cap = srow[250 + 3 * i];
            int   bus = (int)srow[252 + 3 * i];
            float a   = action[b * NCSd + i];
            float conn = cap > 0.f ? 1.f : 0.f;
            float mch = fminf(22.0f,  conn * (70.0f - cap) * 4.0f);
            float mds = fmaxf(-22.0f, conn * (15.0f - cap) * 4.0f);
            float p = fmaxf(fminf(22.17f * a, mch), mds);
            atomicAdd(&ev[e][bus], p);
        }
        __syncthreads();

        float Sre[BT], Sim[BT], vr[BT], vi[BT];
        #pragma unroll
        for (int e = 0; e < BT; ++e) {
            long b = (long)idxs[e];
            float ap = jok ? state[b * SW + 4 + j]   : 0.f;
            float rp = jok ? state[b * SW + 127 + j] : 0.f;
            Sre[e] = (ap + ev[e][j]) * 0.001f;
            Sim[e] = rp * 0.001f;
            vr[e] = 1.f; vi[e] = 0.f;
        }
        for (int it = 0; it < 100; ++it) {
            #pragma unroll
            for (int e = 0; e < BT; ++e) {
                float d = vr[e] * vr[e] + vi[e] * vi[e];
                float inv = 1.0f / d;
                cmat[j][e] = make_float2((Sre[e] * vr[e] + Sim[e] * vi[e]) * inv,
                                         (Sre[e] * vi[e] - Sim[e] * vr[e]) * inv);
            }
            __syncthreads();
            float ar[BT], ai[BT];
            #pragma unroll
            for (int e = 0; e < BT; ++e) { ar[e] = Wre; ai[e] = Wim; }
            for (int k = 0; k < NB1; ++k) {
                float kr = jok ? Kre[j * NB1 + k] : 0.f;
                float ki = jok ? Kim[j * NB1 + k] : 0.f;
                const float4* crow = (const float4*)(&cmat[k][0]);
                #pragma unroll
                for (int eh = 0; eh < BT / 2; ++eh) {
                    float4 c2 = crow[eh];
                    ar[2*eh]   = fmaf(kr, c2.x, fmaf(-ki, c2.y, ar[2*eh]));
                    ai[2*eh]   = fmaf(kr, c2.y, fmaf( ki, c2.x, ai[2*eh]));
                    ar[2*eh+1] = fmaf(kr, c2.z, fmaf(-ki, c2.w, ar[2*eh+1]));
                    ai[2*eh+1] = fmaf(kr, c2.w, fmaf( ki, c2.z, ai[2*eh+1]));
                }
            }
            float md = 0.f;
            #pragma unroll
            for (int e = 0; e < BT; ++e) {
                float vmn = sqrtf(ar[e]*ar[e] + ai[e]*ai[e]);
                float vmo = sqrtf(vr[e]*vr[e] + vi[e]*vi[e]);
                md = fmaxf(md, fabsf(vmn - vmo));
                vr[e] = ar[e]; vi[e] = ai[e];
            }
            #pragma unroll
            for (int off = 32; off; off >>= 1) md = fmaxf(md, __shfl_xor(md, off));
            if ((tid & 63) == 0) red[tid >> 6] = md;
            __syncthreads();
            if (fmaxf(red[0], red[1]) < 1e-6f) break;
        }
        #pragma unroll
        for (int e = 0; e < BT; ++e) {
            float vm = sqrtf(vr[e]*vr[e] + vi[e]*vi[e]);
            vls[j][e] = jok ? fminf(0.f, 0.05f - fabsf(1.0f - vm)) : 0.f;
        }
        __syncthreads();
        if (tid < (int)nv) {
            float s = 0.f;
            for (int k = 0; k < NB1; ++k) s += vls[k][tid];
            long b = (long)idxs[tid];
            out[b] += 1000.0f * s;
        }
        __syncthreads();   // protect ev/idxs/vls reuse next batch
    }
}

// ================= legacy full-solve path (used only if ws too small) =================
__global__ __launch_bounds__(STPB) void k_main(
    const float* __restrict__ action, const float* __restrict__ state,
    const float* __restrict__ Kre, const float* __restrict__ Kim,
    const float* __restrict__ Lre, const float* __restrict__ Lim,
    float* __restrict__ out)
{
    __shared__ float ev[BT][STPB];
    __shared__ float costs_s[BT];
    __shared__ float usat_s[BT];
    __shared__ __align__(16) float2 cmat[STPB][BT + 2];
    __shared__ float vls[STPB][BT + 1];
    __shared__ float red[2];
    const int tid = threadIdx.x;
    const int e0  = blockIdx.x * BT;
    for (int x = tid; x < BT * STPB; x += STPB) ((float*)ev)[x] = 0.f;
    if (tid < BT) { costs_s[tid] = 0.f; usat_s[tid] = 0.f; }
    __syncthreads();
    for (int task = tid; task < BT * NCSd; task += STPB) {
        int e = task / NCSd, i = task - e * NCSd;
        long b = (long)(e0 + e);
        const float* srow = state + b * SW;
        float cap = srow[250 + 3 * i], tleft = srow[251 + 3 * i];
        int bus = (int)srow[252 + 3 * i];
        float a = action[b * NCSd + i];
        float conn = cap > 0.f ? 1.f : 0.f;
        float mch = fminf(22.0f, conn * (70.0f - cap) * 4.0f);
        float mds = fmaxf(-22.0f, conn * (15.0f - cap) * 4.0f);
        float power = fmaxf(fminf(22.17f * a, mch), mds);
        atomicAdd(&costs_s[e], srow[3] * power * 0.25f);
        float nc = ceilf((cap + power * 0.25f) * 100.0f) * 0.01f;
        if (tleft == 1.0f) { float d = nc - 70.0f; atomicAdd(&usat_s[e], -10.0f * d * d); }
        atomicAdd(&ev[e][bus], power);
    }
    __syncthreads();
    const int j = tid;
    const bool jok = j < NB1;
    float Wre = jok ? Lre[j] : 1.0f, Wim = jok ? Lim[j] : 0.0f;
    float Sre[BT], Sim[BT], vr[BT], vi[BT];
    #pragma unroll
    for (int e = 0; e < BT; ++e) {
        long b = (long)(e0 + e);
        float ap = jok ? state[b * SW + 4 + j] : 0.f;
        float rp = jok ? state[b * SW + 127 + j] : 0.f;
        Sre[e] = (ap + ev[e][j]) * 0.001f; Sim[e] = rp * 0.001f;
        vr[e] = 1.f; vi[e] = 0.f;
    }
    for (int it = 0; it < 100; ++it) {
        #pragma unroll
        for (int e = 0; e < BT; ++e) {
            float d = vr[e]*vr[e] + vi[e]*vi[e];
            float inv = 1.0f / d;
            cmat[j][e] = make_float2((Sre[e]*vr[e] + Sim[e]*vi[e]) * inv,
                                     (Sre[e]*vi[e] - Sim[e]*vr[e]) * inv);
        }
        __syncthreads();
        float ar[BT], ai[BT];
        #pragma unroll
        for (int e = 0; e < BT; ++e) { ar[e] = Wre; ai[e] = Wim; }
        for (int k = 0; k < NB1; ++k) {
            float kr = jok ? Kre[j*NB1+k] : 0.f;
            float ki = jok ? Kim[j*NB1+k] : 0.f;
            const float4* crow = (const float4*)(&cmat[k][0]);
            #pragma unroll
            for (int eh = 0; eh < BT / 2; ++eh) {
                float4 c2 = crow[eh];
                ar[2*eh]   = fmaf(kr, c2.x, fmaf(-ki, c2.y, ar[2*eh]));
                ai[2*eh]   = fmaf(kr, c2.y, fmaf( ki, c2.x, ai[2*eh]));
                ar[2*eh+1] = fmaf(kr, c2.z, fmaf(-ki, c2.w, ar[2*eh+1]));
                ai[2*eh+1] = fmaf(kr, c2.w, fmaf( ki, c2.z, ai[2*eh+1]));
            }
        }
        float md = 0.f;
        #pragma unroll
        for (int e = 0; e < BT; ++e) {
            float vmn = sqrtf(ar[e]*ar[e] + ai[e]*ai[e]);
            float vmo = sqrtf(vr[e]*vr[e] + vi[e]*vi[e]);
            md = fmaxf(md, fabsf(vmn - vmo));
            vr[e] = ar[e]; vi[e] = ai[e];
        }
        #pragma unroll
        for (int off = 32; off > 0; off >>= 1) md = fmaxf(md, __shfl_xor(md, off));
        if ((tid & 63) == 0) red[tid >> 6] = md;
        __syncthreads();
        if (fmaxf(red[0], red[1]) < 1e-6f) break;
    }
    #pragma unroll
    for (int e = 0; e < BT; ++e) {
        float vm = sqrtf(vr[e]*vr[e] + vi[e]*vi[e]);
        vls[j][e] = jok ? fminf(0.f, 0.05f - fabsf(1.0f - vm)) : 0.f;
    }
    __syncthreads();
    if (tid < BT) {
        float s = 0.f;
        for (int k = 0; k < NB1; ++k) s += vls[k][tid];
        out[e0 + tid] = 1000.0f * s + costs_s[tid] + usat_s[tid];
    }
}

extern "C" void kernel_launch(void* const* d_in, const int* in_sizes, int n_in,
                              void* d_out, int out_size, void* d_ws, size_t ws_size,
                              hipStream_t stream) {
    const float* action = (const float*)d_in[0];
    const float* state  = (const float*)d_in[1];
    const float* Kre    = (const float*)d_in[2];
    const float* Kim    = (const float*)d_in[3];
    const float* Lre    = (const float*)d_in[4];
    const float* Lim    = (const float*)d_in[5];
    float* out = (float*)d_out;
    const int B = out_size;                        // 32768

    const size_t wsNeed = (size_t)(3 + B) * sizeof(unsigned);
    if (ws_size >= wsNeed) {
        float* ws = (float*)d_ws;
        hipLaunchKernelGGL(k_rowmax, dim3(1), dim3(128), 0, stream, Kre, Kim, Lre, Lim, ws);
        hipLaunchKernelGGL(k_fast, dim3((B + EPB - 1) / EPB), dim3(TPB), 0, stream,
                           action, state, ws, out);
        hipLaunchKernelGGL(k_solve, dim3(2048), dim3(STPB), 0, stream,
                           action, state, Kre, Kim, Lre, Lim, ws, out);
    } else {
        hipLaunchKernelGGL(k_main, dim3((B + BT - 1) / BT), dim3(STPB), 0, stream,
                           action, state, Kre, Kim, Lre, Lim, out);
    }
}